// Round 13
// baseline (246.123 us; speedup 1.0000x reference)
//
#include <hip/hip_runtime.h>
#include <cstdint>
#include <cstddef>

// ---------------------------------------------------------------------------
// PhiAttention: h -> q,k,v (GEMM+bias) -> partial RoPE -> cache scatter ->
// block-diagonal causal attention -> output GEMM+bias.
// T=2048, HID=2560, H=32, D=80, ROT=32, 4 segments of 512, CACHE=4096.
//
// Round 12: front-load ALL 24 per-tile ds_reads into phase 1 (single LGKM0;
// phases 2-4 keep barriers+setprio but lose their lgkm waits, ~200cyc each).
// Hazard-checked: every stage write (stA1(t+1): other buf; stA0/stB0/stB1(t+2):
// issued >=1 barrier after ph1's LGKM0 where all front-loaded reads complete).
// Removes r11's (neutral) LGKM8/4 hints. VGPR +32 (second A-frag set).
// Everything else identical to the verified 242.6us config.
// ---------------------------------------------------------------------------

#define HIDDEN 2560
#define SEQT 2048
#define NHEADS 32
#define DHEAD 80
#define NSEG 4
#define SEGLEN 512
#define CACHE_ROWS 4096
#define QSCALE 0.11180339887498949f  // 80^-0.5

typedef __bf16 bf16_8 __attribute__((ext_vector_type(8)));
typedef unsigned short u16x8 __attribute__((ext_vector_type(8)));
typedef float f32x4 __attribute__((ext_vector_type(4)));

__device__ __forceinline__ unsigned short f2bf(float f) {
  unsigned int u = __builtin_bit_cast(unsigned int, f);
  u += 0x7fffu + ((u >> 16) & 1u);  // RNE
  return (unsigned short)(u >> 16);
}
__device__ __forceinline__ float bf2f(unsigned short s) {
  unsigned int u = ((unsigned int)s) << 16;
  return __builtin_bit_cast(float, u);
}

__device__ __forceinline__ void gload16(const unsigned short* g, unsigned short* l) {
  __builtin_amdgcn_global_load_lds(
      (const __attribute__((address_space(1))) unsigned int*)g,
      (__attribute__((address_space(3))) unsigned int*)l, 16, 0, 0);
}

#define BAR() asm volatile("s_barrier" ::: "memory")
#define LGKM0()                                          \
  do {                                                   \
    asm volatile("s_waitcnt lgkmcnt(0)" ::: "memory");   \
    __builtin_amdgcn_sched_barrier(0);                   \
  } while (0)
#define PRIO(x) __builtin_amdgcn_s_setprio(x)
#define MF(af, bf, c) c = __builtin_amdgcn_mfma_f32_16x16x32_bf16(af, bf, c, 0, 0, 0)

// ---------------------------------------------------------------------------
// prep: z=0..3 cast Wq/Wk/Wv/Wd, z=4 cast h, z=5/6 copy cache upper halves.
// ---------------------------------------------------------------------------
__global__ __launch_bounds__(256) void prep_kernel(
    const float* __restrict__ s0, const float* __restrict__ s1,
    const float* __restrict__ s2, const float* __restrict__ s3,
    const float* __restrict__ s4,
    const float* __restrict__ kci, const float* __restrict__ vci,
    unsigned short* __restrict__ d0, unsigned short* __restrict__ d1,
    unsigned short* __restrict__ d2, unsigned short* __restrict__ d3,
    unsigned short* __restrict__ d4,
    float* __restrict__ kco, float* __restrict__ vco) {
  const int z = blockIdx.z;
  const int stride = gridDim.x * blockDim.x;
  int i = blockIdx.x * blockDim.x + threadIdx.x;
  if (z < 5) {
    const float* s = z == 0 ? s0 : z == 1 ? s1 : z == 2 ? s2 : z == 3 ? s3 : s4;
    unsigned short* d = z == 0 ? d0 : z == 1 ? d1 : z == 2 ? d2 : z == 3 ? d3 : d4;
    const int n4 = (z < 4) ? (HIDDEN * HIDDEN / 4) : (SEQT * HIDDEN / 4);
    for (; i < n4; i += stride) {
      float4 v = ((const float4*)s)[i];
      ushort4 o;
      o.x = f2bf(v.x); o.y = f2bf(v.y); o.z = f2bf(v.z); o.w = f2bf(v.w);
      ((ushort4*)d)[i] = o;
    }
  } else {
    const int n4 = SEQT * HIDDEN / 4;  // upper half of a 4096-row cache
    const float4* s = (const float4*)(z == 5 ? kci : vci);
    float4* d = (float4*)(z == 5 ? kco : vco);
    for (; i < n4; i += stride) d[i + n4] = s[i + n4];
  }
}

// ---------------------------------------------------------------------------
// 8-phase 256x256 GEMM tile body (16x16x32 MFMA):
// C[m][n] = sum_{k in [kbase, kbase+nt*64)} A[m][k]*B[n][k] (+ bias[n]).
// nt EVEN. 512 threads = 8 waves (2M x 4N), per-wave 128x64 (acc[8][4] f32x4).
// LDS 128 KiB: 2 buffers x (A 32KB + B 32KB), BK=64, 128B rows.
// Swizzle: LDS slot c of row r holds global 16B chunk (c-(r&63))&7; readers
// use c0=(kg+l15)&7 (and c0^4 for upper K-half) -> 2-way conflict (free).
// r12: ALL 24 tile ds_reads front-loaded into ph1 (one LGKM0/tile); phases
// 2-4 keep barrier+setprio structure but have no lgkm stall. Stage writes
// verified to land >=1 barrier after the reads of their region complete.
// OUTMODE: 0 = bf16 + bias, 2 = bf16 partial (no bias, split-K).
// ---------------------------------------------------------------------------
template <int OUTMODE>
__device__ __forceinline__ void gemm256_body(
    const unsigned short* __restrict__ A, const unsigned short* __restrict__ Bg,
    const float* __restrict__ bias, void* __restrict__ C,
    int m0, int n0, int kbase, int nt) {
  constexpr int K = HIDDEN;  // row stride
  __shared__ __align__(16) unsigned short L[65536];  // 128 KiB

  const int tid = threadIdx.x;
  const int lane = tid & 63;
  const int wid = tid >> 6;
  const int l15 = lane & 15;
  const int kg = lane >> 4;
  const int wm = wid >> 2;   // 0..1
  const int wn = wid & 3;    // 0..3

  // --- staging (pre-swizzled global source; linear LDS dest) ---
  const int g8 = (((tid & 7) - (tid >> 3)) & 7) * 8;  // global chunk (ushorts)
  const int srow = tid >> 3;                          // 0..63
  const unsigned short* As0 = A + (size_t)(m0 + srow) * K + kbase + g8;
  const unsigned short* As1 = As0 + (size_t)128 * K;
  const unsigned short* Bs0 = Bg + (size_t)(n0 + srow) * K + kbase + g8;
  const unsigned short* Bs1 = Bs0 + (size_t)128 * K;
  const int t16 = tid * 8;  // ushort offset, = tid*16 bytes

  auto stA0 = [&](int kt) {  // LDS A rows {0-63, 128-191}
    const int b = (kt & 1) * 32768, ko = kt * 64;
    gload16(As0 + ko, L + b + t16);
    gload16(As1 + ko, L + b + 8192 + t16);
  };
  auto stA1 = [&](int kt) {  // LDS A rows {64-127, 192-255}
    const int b = (kt & 1) * 32768, ko = 64 * K + kt * 64;
    gload16(As0 + ko, L + b + 4096 + t16);
    gload16(As1 + ko, L + b + 12288 + t16);
  };
  auto stB0 = [&](int kt) {  // LDS B rows {0-63, 64-127}
    const int b = (kt & 1) * 32768 + 16384, ko = kt * 64;
    gload16(Bs0 + ko, L + b + t16);
    gload16(Bs0 + 64 * K + ko, L + b + 4096 + t16);
  };
  auto stB1 = [&](int kt) {  // LDS B rows {128-191, 192-255}
    const int b = (kt & 1) * 32768 + 16384 + 8192, ko = kt * 64;
    gload16(Bs1 + ko, L + b + t16);
    gload16(Bs1 + 64 * K + ko, L + b + 4096 + t16);
  };

  // --- read offsets (ushort units); slot = ((kg+l15)&7), ^4 for upper K-half ---
  const int c0 = (kg + l15) & 7;
  const int aof0 = wm * 8192 + l15 * 64 + c0 * 8;
  const int aof1 = wm * 8192 + l15 * 64 + (c0 ^ 4) * 8;
  const int bof0 = 16384 + wn * 4096 + l15 * 64 + c0 * 8;
  const int bof1 = 16384 + wn * 4096 + l15 * 64 + (c0 ^ 4) * 8;

  f32x4 acc[8][4];
#pragma unroll
  for (int m = 0; m < 8; m++)
#pragma unroll
    for (int n = 0; n < 4; n++) acc[m][n] = f32x4{0.f, 0.f, 0.f, 0.f};

  bf16_8 a0[4][2], a1[4][2], bl[2][2], bh[2][2];

#define DSR(off) (*(const bf16_8*)(L + (off)))
  auto rdAll = [&](int off) {  // 24 x ds_read_b128: both A m-halves + all B
#pragma unroll
    for (int fm = 0; fm < 4; fm++) {
      a0[fm][0] = DSR(off + aof0 + fm * 1024);
      a0[fm][1] = DSR(off + aof1 + fm * 1024);
    }
#pragma unroll
    for (int fn = 0; fn < 2; fn++) {
      bl[fn][0] = DSR(off + bof0 + fn * 1024);
      bl[fn][1] = DSR(off + bof1 + fn * 1024);
    }
#pragma unroll
    for (int fn = 0; fn < 2; fn++) {
      bh[fn][0] = DSR(off + bof0 + (2 + fn) * 1024);
      bh[fn][1] = DSR(off + bof1 + (2 + fn) * 1024);
    }
#pragma unroll
    for (int fm = 0; fm < 4; fm++) {
      a1[fm][0] = DSR(off + 4096 + aof0 + fm * 1024);
      a1[fm][1] = DSR(off + 4096 + aof1 + fm * 1024);
    }
  };
  auto mmq = [&](bf16_8 (&aa)[4][2], int mq, int nq, bf16_8 (&bb)[2][2]) {
#pragma unroll
    for (int fm = 0; fm < 4; fm++)
#pragma unroll
      for (int fn = 0; fn < 2; fn++) {
        MF(aa[fm][0], bb[fn][0], acc[mq * 4 + fm][nq * 2 + fn]);
        MF(aa[fm][1], bb[fn][1], acc[mq * 4 + fm][nq * 2 + fn]);
      }
  };

  // --- prologue: 7 units (tile0 complete + tile1 {A0,B0,B1}), drain to 3 ---
  stA0(0); stB0(0); stB1(0); stA1(0);
  stA0(1); stB0(1); stB1(1);
  asm volatile("s_waitcnt vmcnt(6)" ::: "memory");
  BAR();

  // --- steady: tile t from buf(t&1); stages: A1(t+1),A0(t+2),B0(t+2),B1(t+2) ---
#pragma unroll 2
  for (int t = 0; t < nt - 2; ++t) {
    const int bo = (t & 1) * 32768;
    rdAll(bo);
    stA1(t + 1);
    BAR(); LGKM0(); PRIO(1); mmq(a0, 0, 0, bl); PRIO(0); BAR();
    stA0(t + 2);
    BAR(); PRIO(1); mmq(a0, 0, 1, bh); PRIO(0); BAR();
    stB0(t + 2);
    BAR(); PRIO(1); mmq(a1, 1, 0, bl); PRIO(0); BAR();
    stB1(t + 2);
    BAR(); PRIO(1); mmq(a1, 1, 1, bh); PRIO(0);
    asm volatile("s_waitcnt vmcnt(6)" ::: "memory");
    BAR();
  }

  {  // tile nt-2 (buf0; nt even): last stage unit, then full drain
    rdAll(0);
    stA1(nt - 1);
    BAR(); LGKM0(); PRIO(1); mmq(a0, 0, 0, bl); PRIO(0); BAR();
    BAR(); PRIO(1); mmq(a0, 0, 1, bh); PRIO(0); BAR();
    BAR(); PRIO(1); mmq(a1, 1, 0, bl); PRIO(0); BAR();
    BAR(); PRIO(1); mmq(a1, 1, 1, bh); PRIO(0);
    asm volatile("s_waitcnt vmcnt(0)" ::: "memory");
    BAR();
  }
  {  // tile nt-1 (buf1): pure compute
    rdAll(32768);
    LGKM0();
    PRIO(1); mmq(a0, 0, 0, bl); mmq(a0, 0, 1, bh);
    mmq(a1, 1, 0, bl); mmq(a1, 1, 1, bh); PRIO(0);
  }
#undef DSR

  // --- epilogue: C row = m0+wm*128+m8*16+kg*4+j, col = n0+wn*64+n4*16+l15 ---
#pragma unroll
  for (int n4 = 0; n4 < 4; n4++) {
    const int col = n0 + wn * 64 + n4 * 16 + l15;
    const float bv = (OUTMODE == 2) ? 0.f : bias[col];
#pragma unroll
    for (int m8 = 0; m8 < 8; m8++) {
      const int rowb = m0 + wm * 128 + m8 * 16 + kg * 4;
#pragma unroll
      for (int j = 0; j < 4; j++) {
        float val = acc[m8][n4][j] + bv;
        ((unsigned short*)C)[(size_t)(rowb + j) * HIDDEN + col] = f2bf(val);
      }
    }
  }
}

// QKV: grid (8,10,3) = 240 blocks, XCD-swizzled (240 % 8 == 0 -> bijective).
__global__ __launch_bounds__(512, 2) void gemm_qkv8_kernel(
    const unsigned short* __restrict__ A,
    const unsigned short* __restrict__ B0, const unsigned short* __restrict__ B1,
    const unsigned short* __restrict__ B2,
    const float* __restrict__ bias0, const float* __restrict__ bias1,
    const float* __restrict__ bias2,
    unsigned short* __restrict__ C0, unsigned short* __restrict__ C1,
    unsigned short* __restrict__ C2) {
  const int lb = blockIdx.x + 8 * (blockIdx.y + 10 * blockIdx.z);  // 0..239
  const int swz = (lb & 7) * 30 + (lb >> 3);  // XCD x owns swz [30x, 30x+30)
  const int mx = swz & 7;
  const int r = swz >> 3;
  const int ny = r % 10;
  const int zz = r / 10;
  const unsigned short* B = zz == 0 ? B0 : (zz == 1 ? B1 : B2);
  const float* bias = zz == 0 ? bias0 : (zz == 1 ? bias1 : bias2);
  unsigned short* C = zz == 0 ? C0 : (zz == 1 ? C1 : C2);
  gemm256_body<0>(A, B, bias, C, mx * 256, ny * 256, 0, 40);
}

// Output proj, split-K=3 (k-tiles 14/14/12): grid (8,10,3) = 240 blocks,
// XCD-swizzled. Writes bf16 partials (no bias); reduce3 sums + bias.
__global__ __launch_bounds__(512, 2) void gemm_out8_kernel(
    const unsigned short* __restrict__ A, const unsigned short* __restrict__ B,
    unsigned short* __restrict__ P0, unsigned short* __restrict__ P1,
    unsigned short* __restrict__ P2) {
  const int lb = blockIdx.x + 8 * (blockIdx.y + 10 * blockIdx.z);  // 0..239
  const int swz = (lb & 7) * 30 + (lb >> 3);
  const int mx = swz & 7;
  const int r = swz >> 3;
  const int ny = r % 10;
  const int kz = r / 10;  // k-split
  unsigned short* P = kz == 0 ? P0 : (kz == 1 ? P1 : P2);
  const int kbase = kz * 896;               // 0, 896, 1792
  const int nt = (kz == 2) ? 12 : 14;       // 14+14+12 = 40 tiles = K 2560
  gemm256_body<2>(A, B, nullptr, P, mx * 256, ny * 256, kbase, nt);
}

__global__ __launch_bounds__(256) void reduce3_bias_kernel(
    const unsigned short* __restrict__ p0, const unsigned short* __restrict__ p1,
    const unsigned short* __restrict__ p2, const float* __restrict__ bias,
    float* __restrict__ out, int n8) {
  int i = blockIdx.x * blockDim.x + threadIdx.x;
  const int stride = gridDim.x * blockDim.x;
  for (; i < n8; i += stride) {
    u16x8 a = ((const u16x8*)p0)[i];
    u16x8 b = ((const u16x8*)p1)[i];
    u16x8 c = ((const u16x8*)p2)[i];
    const int cb = (i * 8) % HIDDEN;  // HIDDEN % 8 == 0 -> no wrap
    float4 o0, o1;
#pragma unroll
    for (int e = 0; e < 4; e++) {
      (&o0.x)[e] = bf2f(a[e]) + bf2f(b[e]) + bf2f(c[e]) + bias[cb + e];
      (&o1.x)[e] = bf2f(a[e + 4]) + bf2f(b[e + 4]) + bf2f(c[e + 4]) + bias[cb + 4 + e];
    }
    *(float4*)&out[(size_t)i * 8] = o0;
    *(float4*)&out[(size_t)i * 8 + 4] = o1;
  }
}

// ---------------------------------------------------------------------------
// RoPE (vectorized) + f32 cache scatter for BOTH k and v rows (r7-verified).
// ---------------------------------------------------------------------------
__global__ __launch_bounds__(256) void rope_scatter_kernel(
    unsigned short* __restrict__ qb, unsigned short* __restrict__ kb,
    const unsigned short* __restrict__ vb,
    const int* __restrict__ positions, const int* __restrict__ cidx,
    float* __restrict__ kco, float* __restrict__ vco) {
  const int t = blockIdx.x;
  const int tid = threadIdx.x;
  __shared__ float cs[16], sn[16];

  if (tid < 16) {
    const float pos = (float)positions[t];
    const float inv = expf(-(float)tid * (9.210340371976184f / 16.0f));
    const float f = pos * inv;
    cs[tid] = cosf(f);
    sn[tid] = sinf(f);
  }
  __syncthreads();

  {
    unsigned short* buf = (tid >> 7) ? kb : qb;  // 0..127 q, 128..255 k
    const int r = tid & 127;
    const int head = r >> 2;
    const int d0 = (r & 3) * 4;
    unsigned short* p = buf + (size_t)t * HIDDEN + head * DHEAD + d0;
    ushort4 u1 = *(const ushort4*)p;
    ushort4 u2 = *(const ushort4*)(p + 16);
    ushort4 o1, o2;
#pragma unroll
    for (int e = 0; e < 4; e++) {
      const float c = cs[d0 + e], s = sn[d0 + e];
      const float x1 = bf2f((&u1.x)[e]);
      const float x2 = bf2f((&u2.x)[e]);
      (&o1.x)[e] = f2bf(x1 * c - x2 * s);
      (&o2.x)[e] = f2bf(x2 * c + x1 * s);
    }
    *(ushort4*)p = o1;
    *(ushort4*)(p + 16) = o2;
  }
  __syncthreads();

  const int ci = cidx[t];
  float* krow = kco + (size_t)ci * HIDDEN;
  float* vrow = vco + (size_t)ci * HIDDEN;
  const unsigned short* ks = kb + (size_t)t * HIDDEN;
  const unsigned short* vs = vb + (size_t)t * HIDDEN;
  for (int j = tid; j < 2 * (HIDDEN / 4); j += 256) {  // 1280 float4 jobs
    const int w = j >= (HIDDEN / 4);
    const int e4 = j - w * (HIDDEN / 4);
    const unsigned short* src = (w ? vs : ks) + e4 * 4;
    float* dst = (w ? vrow : krow) + e4 * 4;
    ushort4 u = *(const ushort4*)src;
    float4 f;
    f.x = bf2f(u.x); f.y = bf2f(u.y); f.z = bf2f(u.z); f.w = bf2f(u.w);
    *(float4*)dst = f;
  }
}

// ---------------------------------------------------------------------------
// MFMA flash attention (round-1, verified; Q-load vectorized r8).
// Block = (q-tile 64, head, seg).
// ---------------------------------------------------------------------------
#define KSTR 104
#define VSTR 72
#define PSTR 72

__global__ __launch_bounds__(256) void attn_mfma_kernel(
    const unsigned short* __restrict__ qb, const unsigned short* __restrict__ kb,
    const unsigned short* __restrict__ vb, unsigned short* __restrict__ ob) {
  const int qt = blockIdx.x;
  const int h = blockIdx.y;
  const int seg = blockIdx.z;
  const int tq0 = seg * SEGLEN + qt * 64;

  __shared__ unsigned short Kt[64 * KSTR];
  __shared__ unsigned short VtT[80 * VSTR];
  __shared__ unsigned short Pw[4][16 * PSTR];

  const int tid = threadIdx.x;
  const int lane = tid & 63;
  const int w = tid >> 6;
  const int l15 = lane & 15;
  const int g = lane >> 4;

  bf16_8 qa[3];
  {
    const unsigned short* qp = qb + (size_t)(tq0 + w * 16 + l15) * HIDDEN + h * DHEAD;
#pragma unroll
    for (int c = 0; c < 3; c++) {
      u16x8 t = (u16x8)(unsigned short)0;
      const int d0 = c * 32 + g * 8;
      if (d0 < DHEAD) {
        ushort4 v0 = *(const ushort4*)(qp + d0);
        ushort4 v1 = *(const ushort4*)(qp + d0 + 4);
        t[0] = f2bf(bf2f(v0.x) * QSCALE); t[1] = f2bf(bf2f(v0.y) * QSCALE);
        t[2] = f2bf(bf2f(v0.z) * QSCALE); t[3] = f2bf(bf2f(v0.w) * QSCALE);
        t[4] = f2bf(bf2f(v1.x) * QSCALE); t[5] = f2bf(bf2f(v1.y) * QSCALE);
        t[6] = f2bf(bf2f(v1.z) * QSCALE); t[7] = f2bf(bf2f(v1.w) * QSCALE);
      }
      qa[c] = __builtin_bit_cast(bf16_8, t);
    }
  }

  float m_[4], l_[4];
#pragma unroll
  for (int j = 0; j < 4; j++) { m_[j] = -3.0e38f; l_[j] = 0.f; }
  f32x4 Oacc[5];
#pragma unroll
  for (int n = 0; n < 5; n++) Oacc[n] = f32x4{0.f, 0.f, 0.f, 0.f};

  for (int st = 0; st <= qt; ++st) {
    const int ts0 = seg * SEGLEN + st * 64;
    __syncthreads();
    for (int i = tid; i < 64 * 20; i += 256) {
      const int row = i / 20;
      const int c = i - row * 20;
      const size_t gsrc = (size_t)(ts0 + row) * HIDDEN + h * DHEAD + c * 4;
      ushort4 kv = *(const ushort4*)(kb + gsrc);
      ushort4 vv = *(const ushort4*)(vb + gsrc);
      *(ushort4*)&Kt[row * KSTR + c * 4] = kv;
      VtT[(c * 4 + 0) * VSTR + row] = vv.x;
      VtT[(c * 4 + 1) * VSTR + row] = vv.y;
      VtT[(c * 4 + 2) * VSTR + row] = vv.z;
      VtT[(c * 4 + 3) * VSTR + row] = vv.w;
    }
    __syncthreads();

    f32x4 Sacc[4];
#pragma unroll
    for (int t = 0; t < 4; t++) Sacc[t] = f32x4{0.f, 0.f, 0.f, 0.f};
#pragma unroll
    for (int c = 0; c < 3; c++) {
#pragma unroll
      for (int t = 0; t < 4; t++) {
        bf16_8 kf;
        if (c < 2 || g < 2)
          kf = *(const bf16_8*)&Kt[(t * 16 + l15) * KSTR + c * 32 + g * 8];
        else
          kf = __builtin_bit_cast(bf16_8, (u16x8)(unsigned short)0);
        Sacc[t] = __builtin_amdgcn_mfma_f32_16x16x32_bf16(qa[c], kf, Sacc[t], 0, 0, 0);
      }
    }

    if (st == qt) {
#pragma unroll
      for (int t = 0; t < 4; t++)
#pragma unroll
        for (int j = 0; j < 4; j++)
          if (t * 16 + l15 > w * 16 + 4 * g + j) Sacc[t][j] = -1e30f;
    }

    float pm[4], ps[4], rold[4];
#pragma unroll
    for (int j = 0; j < 4; j++)
      pm[j] = fmaxf(fmaxf(Sacc[0][j], Sacc[1][j]), fmaxf(Sacc[2][j], Sacc[3][j]));
#pragma unroll
    for (int d = 1; d < 16; d <<= 1)
#pragma unroll
      for (int j = 0; j < 4; j++) pm[j] = fmaxf(pm[j], __shfl_xor(pm[j], d, 64));
#pragma unroll
    for (int j = 0; j < 4; j++) {
      const float mn = fmaxf(m_[j], pm[j]);
      rold[j] = __expf(m_[j] - mn);
      m_[j] = mn;
      ps[j] = 0.f;
    }
#pragma unroll
    for (int t = 0; t < 4; t++)
#pragma unroll
      for (int j = 0; j < 4; j++) {
        const float p = __expf(Sacc[t][j] - m_[j]);
        Sacc[t][j] = p;
        ps[j] += p;
      }
#pragma unroll
    for (int d = 1; d < 16; d <<= 1)
#pragma unroll
      for (int j = 0; j < 4; j++) ps[j] += __shfl_xor(ps[j], d, 64);
#pragma unroll
    for (int j = 0; j < 4; j++) l_[j] = l_[j] * rold[j] + ps[j];

#pragma unroll
    for (int t = 0; t < 4; t++)
#pragma unroll
      for (int j = 0; j < 4; j++)
        Pw[w][(4 * g + j) * PSTR + t * 16 + l15] = f2bf(Sacc[t][j]);
#pragma unroll
    for (int n = 0; n < 5; n++)
#pragma unroll
      for (int j = 0; j < 4; j++) Oacc[n][j] *= rold[j];

#pragma unroll
    for (int c = 0; c < 2; c++) {
      bf16_8 pa = *(const bf16_8*)&Pw[w][l15 * PSTR + c * 32 + g * 8];
#pragma unroll
      for (int n = 0; n < 5; n++) {
        bf16_8 vf = *(const bf16_8*)&VtT[(n * 16 + l15) * VSTR + c * 32 + g * 8];
        Oacc[n] = __builtin_amdgcn_mfma_f32_16x16x32_bf16(pa, vf, Oacc[n], 0, 0, 0);
      }
    }
  }

  float inv[4];
#pragma unroll
  for (int j = 0; j < 4; j++) inv[j] = 1.f / l_[j];
  unsigned short* op = ob + (size_t)(tq0 + w * 16) * HIDDEN + h * DHEAD;
#pragma unroll
  for (int n = 0; n < 5; n++)
#pragma unroll
    for (int j = 0; j < 4; j++)
      op[(size_t)(4 * g + j) * HIDDEN + n * 16 + l15] = f2bf(Oacc[n][j] * inv[j]);
}

// ---------------------------------------------------------------------------
// launcher
// ---------------------------------------------------------------------------
extern "C" void kernel_launch(void* const* d_in, const int* in_sizes, int n_in,
                              void* d_out, int out_size, void* d_ws, size_t ws_size,
                              hipStream_t stream) {
  const float* h = (const float*)d_in[0];
  const float* kci = (const float*)d_in[1];
  const float* vci = (const float*)d_in[2];
  const int* positions = (const int*)d_in[3];
  // d_in[4] = offsets: fixed 4x512 segmentation, handled by grid
  const int* cidx = (const int*)d_in[5];
  const float* Wq = (const float*)d_in[6];
  const float* bq = (const float*)d_in[7];
  const float* Wk = (const float*)d_in[8];
  const float* bk = (const float*)d_in[9];
  const float* Wv = (const float*)d_in[10];
  const float* bv = (const float*)d_in[11];
  const float* Wd = (const float*)d_in[12];
  const float* bd = (const float*)d_in[13];

  float* out = (float*)d_out;
  float* kco = out + (size_t)SEQT * HIDDEN;
  float* vco = kco + (size_t)CACHE_ROWS * HIDDEN;

  char* ws = (char*)d_ws;
  char* ws0 = ws;
  unsigned short* h_bf = (unsigned short*)ws;  ws += (size_t)SEQT * HIDDEN * 2;
  unsigned short* Wq_bf = (unsigned short*)ws; ws += (size_t)HIDDEN * HIDDEN * 2;
  unsigned short* Wk_bf = (unsigned short*)ws; ws += (size_t)HIDDEN * HIDDEN * 2;
  unsigned short* Wv_bf = (unsigned short*)ws; ws += (size_t)HIDDEN * HIDDEN * 2;
  unsigned short* Wd_bf = (unsigned short*)ws; ws += (size_t)HIDDEN * HIDDEN * 2;
  unsigned short* q_bf = (unsigned short*)ws;  ws += (size_t)SEQT * HIDDEN * 2;
  unsigned short* k_bf = (unsigned short*)ws;  ws += (size_t)SEQT * HIDDEN * 2;
  unsigned short* v_bf = (unsigned short*)ws;  ws += (size_t)SEQT * HIDDEN * 2;
  unsigned short* o_bf = (unsigned short*)ws;  ws += (size_t)SEQT * HIDDEN * 2;

  // Split-K bf16 partials (10.5MB each) alias DEAD regions at out-GEMM time:
  // p0/p1 over h_bf/Wq_bf (dead); p2 over q_bf (dead after attn).
  // Wd_bf and o_bf stay live (read by the out-GEMM).
  unsigned short* part0 = (unsigned short*)ws0;
  unsigned short* part1 = part0 + (size_t)SEQT * HIDDEN;
  unsigned short* part2 = q_bf;

  {
    dim3 gp(2048, 1, 7);
    prep_kernel<<<gp, 256, 0, stream>>>(Wq, Wk, Wv, Wd, h, kci, vci,
                                        Wq_bf, Wk_bf, Wv_bf, Wd_bf, h_bf,
                                        kco, vco);
  }

  {
    dim3 gq(SEQT / 256, HIDDEN / 256, 3);
    gemm_qkv8_kernel<<<gq, 512, 0, stream>>>(h_bf, Wq_bf, Wk_bf, Wv_bf, bq, bk, bv,
                                             q_bf, k_bf, v_bf);
  }

  rope_scatter_kernel<<<SEQT, 256, 0, stream>>>(q_bf, k_bf, v_bf, positions, cidx,
                                                kco, vco);

  {
    dim3 ga(SEGLEN / 64, NHEADS, NSEG);
    attn_mfma_kernel<<<ga, 256, 0, stream>>>(q_bf, k_bf, v_bf, o_bf);
  }

  {
    dim3 go(SEQT / 256, HIDDEN / 256, 3);
    gemm_out8_kernel<<<go, 512, 0, stream>>>(o_bf, Wd_bf, part0, part1, part2);
  }
  reduce3_bias_kernel<<<2048, 256, 0, stream>>>(part0, part1, part2, bd, out,
                                                SEQT * HIDDEN / 8);
}

// Round 14
// 242.621 us; speedup vs baseline: 1.0144x; 1.0144x over previous
//
#include <hip/hip_runtime.h>
#include <cstdint>
#include <cstddef>

// ---------------------------------------------------------------------------
// PhiAttention: h -> q,k,v (GEMM+bias) -> partial RoPE -> cache scatter ->
// block-diagonal causal attention -> output GEMM+bias.
// T=2048, HID=2560, H=32, D=80, ROT=32, 4 segments of 512, CACHE=4096.
//
// Round 13: REVERT to the round-11 kernel (benched 242.6us in round 12) —
// the empirical optimum. r13's read-front-load was the 5th schedule
// perturbation to regress or go neutral (32x32 MFMA -5us, lgkm-removal
// neutral, epilogue-scatter -13us, front-load -2us, lgkm hints neutral).
// This config: 8-phase 256x256 16x16x32 GEMM w/ per-phase LGKM0, bf16
// split-K=3 out-GEMM, merged prep, vectorized rope+attn-Q.
// ---------------------------------------------------------------------------

#define HIDDEN 2560
#define SEQT 2048
#define NHEADS 32
#define DHEAD 80
#define NSEG 4
#define SEGLEN 512
#define CACHE_ROWS 4096
#define QSCALE 0.11180339887498949f  // 80^-0.5

typedef __bf16 bf16_8 __attribute__((ext_vector_type(8)));
typedef unsigned short u16x8 __attribute__((ext_vector_type(8)));
typedef float f32x4 __attribute__((ext_vector_type(4)));

__device__ __forceinline__ unsigned short f2bf(float f) {
  unsigned int u = __builtin_bit_cast(unsigned int, f);
  u += 0x7fffu + ((u >> 16) & 1u);  // RNE
  return (unsigned short)(u >> 16);
}
__device__ __forceinline__ float bf2f(unsigned short s) {
  unsigned int u = ((unsigned int)s) << 16;
  return __builtin_bit_cast(float, u);
}

__device__ __forceinline__ void gload16(const unsigned short* g, unsigned short* l) {
  __builtin_amdgcn_global_load_lds(
      (const __attribute__((address_space(1))) unsigned int*)g,
      (__attribute__((address_space(3))) unsigned int*)l, 16, 0, 0);
}

#define BAR() asm volatile("s_barrier" ::: "memory")
#define LGKM0()                                          \
  do {                                                   \
    asm volatile("s_waitcnt lgkmcnt(0)" ::: "memory");   \
    __builtin_amdgcn_sched_barrier(0);                   \
  } while (0)
#define LGKM8() asm volatile("s_waitcnt lgkmcnt(8)" ::: "memory")
#define LGKM4() asm volatile("s_waitcnt lgkmcnt(4)" ::: "memory")
#define PRIO(x) __builtin_amdgcn_s_setprio(x)
#define MF(af, bf, c) c = __builtin_amdgcn_mfma_f32_16x16x32_bf16(af, bf, c, 0, 0, 0)

// ---------------------------------------------------------------------------
// prep: z=0..3 cast Wq/Wk/Wv/Wd, z=4 cast h, z=5/6 copy cache upper halves.
// ---------------------------------------------------------------------------
__global__ __launch_bounds__(256) void prep_kernel(
    const float* __restrict__ s0, const float* __restrict__ s1,
    const float* __restrict__ s2, const float* __restrict__ s3,
    const float* __restrict__ s4,
    const float* __restrict__ kci, const float* __restrict__ vci,
    unsigned short* __restrict__ d0, unsigned short* __restrict__ d1,
    unsigned short* __restrict__ d2, unsigned short* __restrict__ d3,
    unsigned short* __restrict__ d4,
    float* __restrict__ kco, float* __restrict__ vco) {
  const int z = blockIdx.z;
  const int stride = gridDim.x * blockDim.x;
  int i = blockIdx.x * blockDim.x + threadIdx.x;
  if (z < 5) {
    const float* s = z == 0 ? s0 : z == 1 ? s1 : z == 2 ? s2 : z == 3 ? s3 : s4;
    unsigned short* d = z == 0 ? d0 : z == 1 ? d1 : z == 2 ? d2 : z == 3 ? d3 : d4;
    const int n4 = (z < 4) ? (HIDDEN * HIDDEN / 4) : (SEQT * HIDDEN / 4);
    for (; i < n4; i += stride) {
      float4 v = ((const float4*)s)[i];
      ushort4 o;
      o.x = f2bf(v.x); o.y = f2bf(v.y); o.z = f2bf(v.z); o.w = f2bf(v.w);
      ((ushort4*)d)[i] = o;
    }
  } else {
    const int n4 = SEQT * HIDDEN / 4;  // upper half of a 4096-row cache
    const float4* s = (const float4*)(z == 5 ? kci : vci);
    float4* d = (float4*)(z == 5 ? kco : vco);
    for (; i < n4; i += stride) d[i + n4] = s[i + n4];
  }
}

// ---------------------------------------------------------------------------
// 8-phase 256x256 GEMM tile body (16x16x32 MFMA, verified r5/r11):
// C[m][n] = sum_{k in [kbase, kbase+nt*64)} A[m][k]*B[n][k] (+ bias[n]).
// nt EVEN. 512 threads = 8 waves (2M x 4N), per-wave 128x64 (acc[8][4] f32x4).
// LDS 128 KiB: 2 buffers x (A 32KB + B 32KB), BK=64, 128B rows.
// Swizzle: LDS slot c of row r holds global 16B chunk (c-(r&63))&7; readers
// use c0=(kg+l15)&7 (and c0^4 for upper K-half) -> 2-way conflict (free).
// Per-phase lgkmcnt(0)+sched_barrier before the MFMA burst is load-bearing.
// OUTMODE: 0 = bf16 + bias, 2 = bf16 partial (no bias, split-K).
// ---------------------------------------------------------------------------
template <int OUTMODE>
__device__ __forceinline__ void gemm256_body(
    const unsigned short* __restrict__ A, const unsigned short* __restrict__ Bg,
    const float* __restrict__ bias, void* __restrict__ C,
    int m0, int n0, int kbase, int nt) {
  constexpr int K = HIDDEN;  // row stride
  __shared__ __align__(16) unsigned short L[65536];  // 128 KiB

  const int tid = threadIdx.x;
  const int lane = tid & 63;
  const int wid = tid >> 6;
  const int l15 = lane & 15;
  const int kg = lane >> 4;
  const int wm = wid >> 2;   // 0..1
  const int wn = wid & 3;    // 0..3

  // --- staging (pre-swizzled global source; linear LDS dest) ---
  const int g8 = (((tid & 7) - (tid >> 3)) & 7) * 8;  // global chunk (ushorts)
  const int srow = tid >> 3;                          // 0..63
  const unsigned short* As0 = A + (size_t)(m0 + srow) * K + kbase + g8;
  const unsigned short* As1 = As0 + (size_t)128 * K;
  const unsigned short* Bs0 = Bg + (size_t)(n0 + srow) * K + kbase + g8;
  const unsigned short* Bs1 = Bs0 + (size_t)128 * K;
  const int t16 = tid * 8;  // ushort offset, = tid*16 bytes

  auto stA0 = [&](int kt) {  // LDS A rows {0-63, 128-191}
    const int b = (kt & 1) * 32768, ko = kt * 64;
    gload16(As0 + ko, L + b + t16);
    gload16(As1 + ko, L + b + 8192 + t16);
  };
  auto stA1 = [&](int kt) {  // LDS A rows {64-127, 192-255}
    const int b = (kt & 1) * 32768, ko = 64 * K + kt * 64;
    gload16(As0 + ko, L + b + 4096 + t16);
    gload16(As1 + ko, L + b + 12288 + t16);
  };
  auto stB0 = [&](int kt) {  // LDS B rows {0-63, 64-127}
    const int b = (kt & 1) * 32768 + 16384, ko = kt * 64;
    gload16(Bs0 + ko, L + b + t16);
    gload16(Bs0 + 64 * K + ko, L + b + 4096 + t16);
  };
  auto stB1 = [&](int kt) {  // LDS B rows {128-191, 192-255}
    const int b = (kt & 1) * 32768 + 16384 + 8192, ko = kt * 64;
    gload16(Bs1 + ko, L + b + t16);
    gload16(Bs1 + 64 * K + ko, L + b + 4096 + t16);
  };

  // --- read offsets (ushort units); slot = ((kg+l15)&7), ^4 for upper K-half ---
  const int c0 = (kg + l15) & 7;
  const int aof0 = wm * 8192 + l15 * 64 + c0 * 8;
  const int aof1 = wm * 8192 + l15 * 64 + (c0 ^ 4) * 8;
  const int bof0 = 16384 + wn * 4096 + l15 * 64 + c0 * 8;
  const int bof1 = 16384 + wn * 4096 + l15 * 64 + (c0 ^ 4) * 8;

  f32x4 acc[8][4];
#pragma unroll
  for (int m = 0; m < 8; m++)
#pragma unroll
    for (int n = 0; n < 4; n++) acc[m][n] = f32x4{0.f, 0.f, 0.f, 0.f};

  bf16_8 a[4][2], bl[2][2], bh[2][2];

#define DSR(off) (*(const bf16_8*)(L + (off)))
  auto rdA = [&](int off) {  // 8 x ds_read_b128
#pragma unroll
    for (int fm = 0; fm < 4; fm++) {
      a[fm][0] = DSR(off + aof0 + fm * 1024);
      a[fm][1] = DSR(off + aof1 + fm * 1024);
    }
  };
  auto rdBl = [&](int off) {  // 4 x ds_read_b128 (fn 0,1)
#pragma unroll
    for (int fn = 0; fn < 2; fn++) {
      bl[fn][0] = DSR(off + bof0 + fn * 1024);
      bl[fn][1] = DSR(off + bof1 + fn * 1024);
    }
  };
  auto rdBh = [&](int off) {  // 4 x ds_read_b128 (fn 2,3)
#pragma unroll
    for (int fn = 0; fn < 2; fn++) {
      bh[fn][0] = DSR(off + bof0 + (2 + fn) * 1024);
      bh[fn][1] = DSR(off + bof1 + (2 + fn) * 1024);
    }
  };
  auto mmq = [&](int mq, int nq, bf16_8 (&bb)[2][2]) {  // 16 MFMA
#pragma unroll
    for (int fm = 0; fm < 4; fm++)
#pragma unroll
      for (int fn = 0; fn < 2; fn++) {
        MF(a[fm][0], bb[fn][0], acc[mq * 4 + fm][nq * 2 + fn]);
        MF(a[fm][1], bb[fn][1], acc[mq * 4 + fm][nq * 2 + fn]);
      }
  };

  // --- prologue: 7 units (tile0 complete + tile1 {A0,B0,B1}), drain to 3 ---
  stA0(0); stB0(0); stB1(0); stA1(0);
  stA0(1); stB0(1); stB1(1);
  asm volatile("s_waitcnt vmcnt(6)" ::: "memory");
  BAR();

  // --- steady: tile t from buf(t&1); stages: A1(t+1),A0(t+2),B0(t+2),B1(t+2) ---
#pragma unroll 2
  for (int t = 0; t < nt - 2; ++t) {
    const int bo = (t & 1) * 32768;
    rdA(bo); rdBl(bo);
    stA1(t + 1);
    LGKM8();
    BAR(); LGKM0(); PRIO(1); mmq(0, 0, bl); PRIO(0); BAR();
    rdBh(bo);
    stA0(t + 2);
    BAR(); LGKM0(); PRIO(1); mmq(0, 1, bh); PRIO(0); BAR();
    rdA(bo + 4096);
    stB0(t + 2);
    LGKM4();
    BAR(); LGKM0(); PRIO(1); mmq(1, 0, bl); PRIO(0); BAR();
    stB1(t + 2);
    BAR(); PRIO(1); mmq(1, 1, bh); PRIO(0);
    asm volatile("s_waitcnt vmcnt(6)" ::: "memory");
    BAR();
  }

  {  // tile nt-2 (buf0; nt even): last stage unit, then full drain
    const int bo = 0;
    rdA(bo); rdBl(bo);
    stA1(nt - 1);
    LGKM8();
    BAR(); LGKM0(); PRIO(1); mmq(0, 0, bl); PRIO(0); BAR();
    rdBh(bo);
    BAR(); LGKM0(); PRIO(1); mmq(0, 1, bh); PRIO(0); BAR();
    rdA(bo + 4096);
    LGKM4();
    BAR(); LGKM0(); PRIO(1); mmq(1, 0, bl); PRIO(0); BAR();
    BAR(); PRIO(1); mmq(1, 1, bh); PRIO(0);
    asm volatile("s_waitcnt vmcnt(0)" ::: "memory");
    BAR();
  }
  {  // tile nt-1 (buf1): pure compute
    const int bo = 32768;
    rdA(bo); rdBl(bo);
    LGKM8();
    BAR(); LGKM0(); PRIO(1); mmq(0, 0, bl); PRIO(0); BAR();
    rdBh(bo);
    BAR(); LGKM0(); PRIO(1); mmq(0, 1, bh); PRIO(0); BAR();
    rdA(bo + 4096);
    LGKM4();
    BAR(); LGKM0(); PRIO(1); mmq(1, 0, bl); PRIO(0); BAR();
    PRIO(1); mmq(1, 1, bh); PRIO(0);
  }
#undef DSR

  // --- epilogue: C row = m0+wm*128+m8*16+kg*4+j, col = n0+wn*64+n4*16+l15 ---
#pragma unroll
  for (int n4 = 0; n4 < 4; n4++) {
    const int col = n0 + wn * 64 + n4 * 16 + l15;
    const float bv = (OUTMODE == 2) ? 0.f : bias[col];
#pragma unroll
    for (int m8 = 0; m8 < 8; m8++) {
      const int rowb = m0 + wm * 128 + m8 * 16 + kg * 4;
#pragma unroll
      for (int j = 0; j < 4; j++) {
        float val = acc[m8][n4][j] + bv;
        ((unsigned short*)C)[(size_t)(rowb + j) * HIDDEN + col] = f2bf(val);
      }
    }
  }
}

// QKV: grid (8,10,3) = 240 blocks, XCD-swizzled (240 % 8 == 0 -> bijective).
__global__ __launch_bounds__(512, 2) void gemm_qkv8_kernel(
    const unsigned short* __restrict__ A,
    const unsigned short* __restrict__ B0, const unsigned short* __restrict__ B1,
    const unsigned short* __restrict__ B2,
    const float* __restrict__ bias0, const float* __restrict__ bias1,
    const float* __restrict__ bias2,
    unsigned short* __restrict__ C0, unsigned short* __restrict__ C1,
    unsigned short* __restrict__ C2) {
  const int lb = blockIdx.x + 8 * (blockIdx.y + 10 * blockIdx.z);  // 0..239
  const int swz = (lb & 7) * 30 + (lb >> 3);  // XCD x owns swz [30x, 30x+30)
  const int mx = swz & 7;
  const int r = swz >> 3;
  const int ny = r % 10;
  const int zz = r / 10;
  const unsigned short* B = zz == 0 ? B0 : (zz == 1 ? B1 : B2);
  const float* bias = zz == 0 ? bias0 : (zz == 1 ? bias1 : bias2);
  unsigned short* C = zz == 0 ? C0 : (zz == 1 ? C1 : C2);
  gemm256_body<0>(A, B, bias, C, mx * 256, ny * 256, 0, 40);
}

// Output proj, split-K=3 (k-tiles 14/14/12): grid (8,10,3) = 240 blocks,
// XCD-swizzled. Writes bf16 partials (no bias); reduce3 sums + bias.
__global__ __launch_bounds__(512, 2) void gemm_out8_kernel(
    const unsigned short* __restrict__ A, const unsigned short* __restrict__ B,
    unsigned short* __restrict__ P0, unsigned short* __restrict__ P1,
    unsigned short* __restrict__ P2) {
  const int lb = blockIdx.x + 8 * (blockIdx.y + 10 * blockIdx.z);  // 0..239
  const int swz = (lb & 7) * 30 + (lb >> 3);
  const int mx = swz & 7;
  const int r = swz >> 3;
  const int ny = r % 10;
  const int kz = r / 10;  // k-split
  unsigned short* P = kz == 0 ? P0 : (kz == 1 ? P1 : P2);
  const int kbase = kz * 896;               // 0, 896, 1792
  const int nt = (kz == 2) ? 12 : 14;       // 14+14+12 = 40 tiles = K 2560
  gemm256_body<2>(A, B, nullptr, P, mx * 256, ny * 256, kbase, nt);
}

__global__ __launch_bounds__(256) void reduce3_bias_kernel(
    const unsigned short* __restrict__ p0, const unsigned short* __restrict__ p1,
    const unsigned short* __restrict__ p2, const float* __restrict__ bias,
    float* __restrict__ out, int n8) {
  int i = blockIdx.x * blockDim.x + threadIdx.x;
  const int stride = gridDim.x * blockDim.x;
  for (; i < n8; i += stride) {
    u16x8 a = ((const u16x8*)p0)[i];
    u16x8 b = ((const u16x8*)p1)[i];
    u16x8 c = ((const u16x8*)p2)[i];
    const int cb = (i * 8) % HIDDEN;  // HIDDEN % 8 == 0 -> no wrap
    float4 o0, o1;
#pragma unroll
    for (int e = 0; e < 4; e++) {
      (&o0.x)[e] = bf2f(a[e]) + bf2f(b[e]) + bf2f(c[e]) + bias[cb + e];
      (&o1.x)[e] = bf2f(a[e + 4]) + bf2f(b[e + 4]) + bf2f(c[e + 4]) + bias[cb + 4 + e];
    }
    *(float4*)&out[(size_t)i * 8] = o0;
    *(float4*)&out[(size_t)i * 8 + 4] = o1;
  }
}

// ---------------------------------------------------------------------------
// RoPE (vectorized) + f32 cache scatter for BOTH k and v rows (r7-verified).
// ---------------------------------------------------------------------------
__global__ __launch_bounds__(256) void rope_scatter_kernel(
    unsigned short* __restrict__ qb, unsigned short* __restrict__ kb,
    const unsigned short* __restrict__ vb,
    const int* __restrict__ positions, const int* __restrict__ cidx,
    float* __restrict__ kco, float* __restrict__ vco) {
  const int t = blockIdx.x;
  const int tid = threadIdx.x;
  __shared__ float cs[16], sn[16];

  if (tid < 16) {
    const float pos = (float)positions[t];
    const float inv = expf(-(float)tid * (9.210340371976184f / 16.0f));
    const float f = pos * inv;
    cs[tid] = cosf(f);
    sn[tid] = sinf(f);
  }
  __syncthreads();

  {
    unsigned short* buf = (tid >> 7) ? kb : qb;  // 0..127 q, 128..255 k
    const int r = tid & 127;
    const int head = r >> 2;
    const int d0 = (r & 3) * 4;
    unsigned short* p = buf + (size_t)t * HIDDEN + head * DHEAD + d0;
    ushort4 u1 = *(const ushort4*)p;
    ushort4 u2 = *(const ushort4*)(p + 16);
    ushort4 o1, o2;
#pragma unroll
    for (int e = 0; e < 4; e++) {
      const float c = cs[d0 + e], s = sn[d0 + e];
      const float x1 = bf2f((&u1.x)[e]);
      const float x2 = bf2f((&u2.x)[e]);
      (&o1.x)[e] = f2bf(x1 * c - x2 * s);
      (&o2.x)[e] = f2bf(x2 * c + x1 * s);
    }
    *(ushort4*)p = o1;
    *(ushort4*)(p + 16) = o2;
  }
  __syncthreads();

  const int ci = cidx[t];
  float* krow = kco + (size_t)ci * HIDDEN;
  float* vrow = vco + (size_t)ci * HIDDEN;
  const unsigned short* ks = kb + (size_t)t * HIDDEN;
  const unsigned short* vs = vb + (size_t)t * HIDDEN;
  for (int j = tid; j < 2 * (HIDDEN / 4); j += 256) {  // 1280 float4 jobs
    const int w = j >= (HIDDEN / 4);
    const int e4 = j - w * (HIDDEN / 4);
    const unsigned short* src = (w ? vs : ks) + e4 * 4;
    float* dst = (w ? vrow : krow) + e4 * 4;
    ushort4 u = *(const ushort4*)src;
    float4 f;
    f.x = bf2f(u.x); f.y = bf2f(u.y); f.z = bf2f(u.z); f.w = bf2f(u.w);
    *(float4*)dst = f;
  }
}

// ---------------------------------------------------------------------------
// MFMA flash attention (round-1, verified; Q-load vectorized r8).
// Block = (q-tile 64, head, seg).
// ---------------------------------------------------------------------------
#define KSTR 104
#define VSTR 72
#define PSTR 72

__global__ __launch_bounds__(256) void attn_mfma_kernel(
    const unsigned short* __restrict__ qb, const unsigned short* __restrict__ kb,
    const unsigned short* __restrict__ vb, unsigned short* __restrict__ ob) {
  const int qt = blockIdx.x;
  const int h = blockIdx.y;
  const int seg = blockIdx.z;
  const int tq0 = seg * SEGLEN + qt * 64;

  __shared__ unsigned short Kt[64 * KSTR];
  __shared__ unsigned short VtT[80 * VSTR];
  __shared__ unsigned short Pw[4][16 * PSTR];

  const int tid = threadIdx.x;
  const int lane = tid & 63;
  const int w = tid >> 6;
  const int l15 = lane & 15;
  const int g = lane >> 4;

  bf16_8 qa[3];
  {
    const unsigned short* qp = qb + (size_t)(tq0 + w * 16 + l15) * HIDDEN + h * DHEAD;
#pragma unroll
    for (int c = 0; c < 3; c++) {
      u16x8 t = (u16x8)(unsigned short)0;
      const int d0 = c * 32 + g * 8;
      if (d0 < DHEAD) {
        ushort4 v0 = *(const ushort4*)(qp + d0);
        ushort4 v1 = *(const ushort4*)(qp + d0 + 4);
        t[0] = f2bf(bf2f(v0.x) * QSCALE); t[1] = f2bf(bf2f(v0.y) * QSCALE);
        t[2] = f2bf(bf2f(v0.z) * QSCALE); t[3] = f2bf(bf2f(v0.w) * QSCALE);
        t[4] = f2bf(bf2f(v1.x) * QSCALE); t[5] = f2bf(bf2f(v1.y) * QSCALE);
        t[6] = f2bf(bf2f(v1.z) * QSCALE); t[7] = f2bf(bf2f(v1.w) * QSCALE);
      }
      qa[c] = __builtin_bit_cast(bf16_8, t);
    }
  }

  float m_[4], l_[4];
#pragma unroll
  for (int j = 0; j < 4; j++) { m_[j] = -3.0e38f; l_[j] = 0.f; }
  f32x4 Oacc[5];
#pragma unroll
  for (int n = 0; n < 5; n++) Oacc[n] = f32x4{0.f, 0.f, 0.f, 0.f};

  for (int st = 0; st <= qt; ++st) {
    const int ts0 = seg * SEGLEN + st * 64;
    __syncthreads();
    for (int i = tid; i < 64 * 20; i += 256) {
      const int row = i / 20;
      const int c = i - row * 20;
      const size_t gsrc = (size_t)(ts0 + row) * HIDDEN + h * DHEAD + c * 4;
      ushort4 kv = *(const ushort4*)(kb + gsrc);
      ushort4 vv = *(const ushort4*)(vb + gsrc);
      *(ushort4*)&Kt[row * KSTR + c * 4] = kv;
      VtT[(c * 4 + 0) * VSTR + row] = vv.x;
      VtT[(c * 4 + 1) * VSTR + row] = vv.y;
      VtT[(c * 4 + 2) * VSTR + row] = vv.z;
      VtT[(c * 4 + 3) * VSTR + row] = vv.w;
    }
    __syncthreads();

    f32x4 Sacc[4];
#pragma unroll
    for (int t = 0; t < 4; t++) Sacc[t] = f32x4{0.f, 0.f, 0.f, 0.f};
#pragma unroll
    for (int c = 0; c < 3; c++) {
#pragma unroll
      for (int t = 0; t < 4; t++) {
        bf16_8 kf;
        if (c < 2 || g < 2)
          kf = *(const bf16_8*)&Kt[(t * 16 + l15) * KSTR + c * 32 + g * 8];
        else
          kf = __builtin_bit_cast(bf16_8, (u16x8)(unsigned short)0);
        Sacc[t] = __builtin_amdgcn_mfma_f32_16x16x32_bf16(qa[c], kf, Sacc[t], 0, 0, 0);
      }
    }

    if (st == qt) {
#pragma unroll
      for (int t = 0; t < 4; t++)
#pragma unroll
        for (int j = 0; j < 4; j++)
          if (t * 16 + l15 > w * 16 + 4 * g + j) Sacc[t][j] = -1e30f;
    }

    float pm[4], ps[4], rold[4];
#pragma unroll
    for (int j = 0; j < 4; j++)
      pm[j] = fmaxf(fmaxf(Sacc[0][j], Sacc[1][j]), fmaxf(Sacc[2][j], Sacc[3][j]));
#pragma unroll
    for (int d = 1; d < 16; d <<= 1)
#pragma unroll
      for (int j = 0; j < 4; j++) pm[j] = fmaxf(pm[j], __shfl_xor(pm[j], d, 64));
#pragma unroll
    for (int j = 0; j < 4; j++) {
      const float mn = fmaxf(m_[j], pm[j]);
      rold[j] = __expf(m_[j] - mn);
      m_[j] = mn;
      ps[j] = 0.f;
    }
#pragma unroll
    for (int t = 0; t < 4; t++)
#pragma unroll
      for (int j = 0; j < 4; j++) {
        const float p = __expf(Sacc[t][j] - m_[j]);
        Sacc[t][j] = p;
        ps[j] += p;
      }
#pragma unroll
    for (int d = 1; d < 16; d <<= 1)
#pragma unroll
      for (int j = 0; j < 4; j++) ps[j] += __shfl_xor(ps[j], d, 64);
#pragma unroll
    for (int j = 0; j < 4; j++) l_[j] = l_[j] * rold[j] + ps[j];

#pragma unroll
    for (int t = 0; t < 4; t++)
#pragma unroll
      for (int j = 0; j < 4; j++)
        Pw[w][(4 * g + j) * PSTR + t * 16 + l15] = f2bf(Sacc[t][j]);
#pragma unroll
    for (int n = 0; n < 5; n++)
#pragma unroll
      for (int j = 0; j < 4; j++) Oacc[n][j] *= rold[j];

#pragma unroll
    for (int c = 0; c < 2; c++) {
      bf16_8 pa = *(const bf16_8*)&Pw[w][l15 * PSTR + c * 32 + g * 8];
#pragma unroll
      for (int n = 0; n < 5; n++) {
        bf16_8 vf = *(const bf16_8*)&VtT[(n * 16 + l15) * VSTR + c * 32 + g * 8];
        Oacc[n] = __builtin_amdgcn_mfma_f32_16x16x32_bf16(pa, vf, Oacc[n], 0, 0, 0);
      }
    }
  }

  float inv[4];
#pragma unroll
  for (int j = 0; j < 4; j++) inv[j] = 1.f / l_[j];
  unsigned short* op = ob + (size_t)(tq0 + w * 16) * HIDDEN + h * DHEAD;
#pragma unroll
  for (int n = 0; n < 5; n++)
#pragma unroll
    for (int j = 0; j < 4; j++)
      op[(size_t)(4 * g + j) * HIDDEN + n * 16 + l15] = f2bf(Oacc[n][j] * inv[j]);
}

// ---------------------------------------------------------------------------
// launcher
// ---------------------------------------------------------------------------
extern "C" void kernel_launch(void* const* d_in, const int* in_sizes, int n_in,
                              void* d_out, int out_size, void* d_ws, size_t ws_size,
                              hipStream_t stream) {
  const float* h = (const float*)d_in[0];
  const float* kci = (const float*)d_in[1];
  const float* vci = (const float*)d_in[2];
  const int* positions = (const int*)d_in[3];
  // d_in[4] = offsets: fixed 4x512 segmentation, handled by grid
  const int* cidx = (const int*)d_in[5];
  const float* Wq = (const float*)d_in[6];
  const float* bq = (const float*)d_in[7];
  const float* Wk = (const float*)d_in[8];
  const float* bk = (const float*)d_in[9];
  const float* Wv = (const float*)d_in[10];
  const float* bv = (const float*)d_in[11];
  const float* Wd = (const float*)d_in[12];
  const float* bd = (const float*)d_in[13];

  float* out = (float*)d_out;
  float* kco = out + (size_t)SEQT * HIDDEN;
  float* vco = kco + (size_t)CACHE_ROWS * HIDDEN;

  char* ws = (char*)d_ws;
  char* ws0 = ws;
  unsigned short* h_bf = (unsigned short*)ws;  ws += (size_t)SEQT * HIDDEN * 2;
  unsigned short* Wq_bf = (unsigned short*)ws; ws += (size_t)HIDDEN * HIDDEN * 2;
  unsigned short* Wk_bf = (unsigned short*)ws; ws += (size_t)HIDDEN * HIDDEN * 2;
  unsigned short* Wv_bf = (unsigned short*)ws; ws += (size_t)HIDDEN * HIDDEN * 2;
  unsigned short* Wd_bf = (unsigned short*)ws; ws += (size_t)HIDDEN * HIDDEN * 2;
  unsigned short* q_bf = (unsigned short*)ws;  ws += (size_t)SEQT * HIDDEN * 2;
  unsigned short* k_bf = (unsigned short*)ws;  ws += (size_t)SEQT * HIDDEN * 2;
  unsigned short* v_bf = (unsigned short*)ws;  ws += (size_t)SEQT * HIDDEN * 2;
  unsigned short* o_bf = (unsigned short*)ws;  ws += (size_t)SEQT * HIDDEN * 2;

  // Split-K bf16 partials (10.5MB each) alias DEAD regions at out-GEMM time:
  // p0/p1 over h_bf/Wq_bf (dead); p2 over q_bf (dead after attn).
  // Wd_bf and o_bf stay live (read by the out-GEMM).
  unsigned short* part0 = (unsigned short*)ws0;
  unsigned short* part1 = part0 + (size_t)SEQT * HIDDEN;
  unsigned short* part2 = q_bf;

  {
    dim3 gp(2048, 1, 7);
    prep_kernel<<<gp, 256, 0, stream>>>(Wq, Wk, Wv, Wd, h, kci, vci,
                                        Wq_bf, Wk_bf, Wv_bf, Wd_bf, h_bf,
                                        kco, vco);
  }

  {
    dim3 gq(SEQT / 256, HIDDEN / 256, 3);
    gemm_qkv8_kernel<<<gq, 512, 0, stream>>>(h_bf, Wq_bf, Wk_bf, Wv_bf, bq, bk, bv,
                                             q_bf, k_bf, v_bf);
  }

  rope_scatter_kernel<<<SEQT, 256, 0, stream>>>(q_bf, k_bf, v_bf, positions, cidx,
                                                kco, vco);

  {
    dim3 ga(SEGLEN / 64, NHEADS, NSEG);
    attn_mfma_kernel<<<ga, 256, 0, stream>>>(q_bf, k_bf, v_bf, o_bf);
  }

  {
    dim3 go(SEQT / 256, HIDDEN / 256, 3);
    gemm_out8_kernel<<<go, 512, 0, stream>>>(o_bf, Wd_bf, part0, part1, part2);
  }
  reduce3_bias_kernel<<<2048, 256, 0, stream>>>(part0, part1, part2, bd, out,
                                                SEQT * HIDDEN / 8);
}